// Round 8
// baseline (160.378 us; speedup 1.0000x reference)
//
#include <hip/hip_runtime.h>
#include <math.h>

#define DD 160
#define HH 160
#define WW 160
#define NB 2
#define NEL (NB*DD*HH*WW)   // 8,192,000 voxels

#define XT 32               // x outputs per block
#define YT 16               // y outputs per block (4 waves x 4 rows)
#define YTW 4               // y outputs per WAVE
#define ZC 16               // z outputs per block
#define NTHR 256
#define NZCH (DD/ZC)        // 10
#define GX (WW/XT)          // 5
#define GY (HH/YT)          // 10
#define NBLK (GX*GY*NB*NZCH)   // 1000 blocks x 4 waves = 4000 waves
#define NPART NBLK

#define WHR 10              // wave halo rows (4 + 6)
#define CP 35               // LDS physical pitch in float4 (32 + swizzle)

typedef float v2f __attribute__((ext_vector_type(2)));

struct G7 { float g[7]; };

// Fully fused separable 3D SSIM, v14b = wave-autonomous, barrier-free loop.
// (v14 failed to COMPILE -- cwsB_helper macro defined below the kernel;
//  jobB's swizzle base is identical to jobA's, so it is simply cwsA.
//  No design change; R6 theory carries over.)
//  * v7-v13 POST-MORTEM: dur ∝ block-slice count (~2.7us/1000) and is
//    INSENSITIVE to instruction volume (v13: -12% VALU-cycles, dur flat),
//    barrier count (v11/v12), LDS size (v11), prefetch depth (v10), grid
//    (v9). Per-CU: 1 block-slice per ~1675cy at ~2.75-block concurrency
//    -> ~4600cy per-slice latency chain per block. The one constant never
//    varied: 4 barrier-COUPLED waves per block. Within a block the slice
//    pipeline is serialized across all 4 waves; independent streams/CU =
//    blocks (~2.75), not waves.
//  * v14: each wave owns a private 32x4 sub-tile + private LDS x-conv
//    buffer [WHR=10][CP]. x-conv->y-conv handoff is within-wave (DS ops
//    of a wave complete in order; one lgkmcnt(0) guards it). ZERO
//    __syncthreads in the slice loop -> ~11 independent wave streams/CU.
//    Cost: y-halo per wave (10 rows / 4 outputs) -> x-conv x1.82, total
//    VALU +29%. Win if VALUBusy 45 -> 70-90.
//  * frozen: XCD swizzle, v2f pk-fma, LDS col swizzle, z-rings, hoisted
//    geometry (v13), epilogue.
__global__ __launch_bounds__(NTHR, 4) void ssim_fused(
        const float* __restrict__ p, const float* __restrict__ t,
        float* __restrict__ partial, G7 gw) {
    const int tid  = threadIdx.x;
    const int wid  = tid >> 6;           // wave 0..3
    const int lane = tid & 63;
    const int tx   = lane & 31;          // output column
    const int tyo2 = lane >> 5;          // 0..1: owns rows 2tyo2, 2tyo2+1 of wave tile

    // XCD-aware work remap (bijection on [0,1000), 1000 % 8 == 0)
    const int flat = blockIdx.x;
    const int w = (flat & 7) * (NBLK / 8) + (flat >> 3);
    const int bx = w % GX;
    const int by = (w / GX) % GY;
    const int bz = w / (GX * GY);        // 0..19

    const int x0  = bx * XT;
    const int wy0 = by * YT + wid * YTW; // wave's first output row
    const int n   = bz / NZCH;
    const int zs  = (bz % NZCH) * ZC;

    __shared__ float4 xw[4][WHR][CP];    // wave-private buffers, 22,400 B

    // z rings: [y-out][slot], slot5 freshest (2 outputs per lane)
    v2f r01[2][6], r23[2][6];
#pragma unroll
    for (int yo = 0; yo < 2; ++yo)
#pragma unroll
        for (int j = 0; j < 6; ++j) {
            r01[yo][j] = (v2f)(0.f);
            r23[yo][j] = (v2f)(0.f);
        }

    const float C1v = 1e-4f, C2v = 9e-4f;
    float ssum = 0.f;
    const int hw = HH * WW;
    const float* pv = p + (size_t)n * DD * hw;
    const float* tv = t + (size_t)n * DD * hw;

    // ---- x-conv job geometry, hoisted (slice-invariant) ----
    // jobA: all 64 lanes, buffer rows 0..7.  jobB: lanes 0..15, rows 8..9.
    const int wrA  = lane >> 3;              // 0..7
    const int bxgA = lane & 7;
    const int gyA  = wy0 + wrA - 3;
    const bool gokA = (unsigned)gyA < (unsigned)HH;
    const int cbA  = x0 + 4 * bxgA - 4;
    bool qvA[3]; int qoffA[3];
#pragma unroll
    for (int q = 0; q < 3; ++q) {
        const int c0 = cbA + 4 * q;
        qvA[q] = gokA && ((unsigned)c0 < (unsigned)WW);
        qoffA[q] = gyA * WW + c0;
    }
    const int cwsA = 4 * bxgA + (bxgA >> 1);

    const bool hasB = lane < 16;
    const int wrB  = 8 + (lane >> 3);        // 8..9 (meaningful only lane<16)
    const int gyB  = wy0 + wrB - 3;
    const bool gokB = hasB && ((unsigned)gyB < (unsigned)HH);
    bool qvB[3]; int qoffB[3];
#pragma unroll
    for (int q = 0; q < 3; ++q) {
        const int c0 = cbA + 4 * q;          // same column group as jobA
        qvB[q] = gokB && ((unsigned)c0 < (unsigned)WW);
        qoffB[q] = gyB * WW + c0;
    }

    const int pcr = tx + (tx >> 3);          // swizzled read column

    // x-conv one job: load 12 cols of p,t -> 4 outputs -> wave-private LDS
    auto xconv = [&](const float* ps, const float* ts,
                     const bool (&qv)[3], const int (&qoff)[3],
                     int wr, int cws) {
        float4 A[3], Bv[3];
#pragma unroll
        for (int q = 0; q < 3; ++q) {
            A[q]  = make_float4(0.f, 0.f, 0.f, 0.f);
            Bv[q] = make_float4(0.f, 0.f, 0.f, 0.f);
            if (qv[q]) {
                A[q]  = *(const float4*)(ps + qoff[q]);
                Bv[q] = *(const float4*)(ts + qoff[q]);
            }
        }
        v2f s01[4], s23[4];
#pragma unroll
        for (int e = 0; e < 4; ++e) { s01[e] = (v2f)(0.f); s23[e] = (v2f)(0.f); }
#pragma unroll
        for (int q = 0; q < 3; ++q) {
            const float af[4] = {A[q].x, A[q].y, A[q].z, A[q].w};
            const float bf[4] = {Bv[q].x, Bv[q].y, Bv[q].z, Bv[q].w};
#pragma unroll
            for (int j = 0; j < 4; ++j) {
                const int i = 4 * q + j;     // loaded position 0..11
                v2f pt; pt[0] = af[j]; pt[1] = bf[j];
                v2f ud; ud[0] = af[j] + bf[j]; ud[1] = af[j] - bf[j];
                v2f qu = ud * ud;
#pragma unroll
                for (int e = 0; e < 4; ++e) {
                    const int k = i - e - 1;  // tap index
                    if (k >= 0 && k < 7) {
                        s01[e] = gw.g[k] * pt + s01[e];
                        s23[e] = gw.g[k] * qu + s23[e];
                    }
                }
            }
        }
#pragma unroll
        for (int e = 0; e < 4; ++e) {
            xw[wid][wr][cws + e] =
                make_float4(s01[e][0], s01[e][1], s23[e][0], s23[e][1]);
        }
    };

    for (int s = zs - 3; s < zs + ZC + 3; ++s) {
        const bool valid = (s >= 0) && (s < DD);   // wave-uniform

        v2f m01[2], m23[2];
#pragma unroll
        for (int yo = 0; yo < 2; ++yo) {
            m01[yo] = (v2f)(0.f);
            m23[yo] = (v2f)(0.f);
        }

        if (valid) {
            const float* ps = pv + (size_t)s * hw;
            const float* ts = tv + (size_t)s * hw;

            // ---- B: x-conv into wave-private LDS (no barrier) ----
            xconv(ps, ts, qvA, qoffA, wrA, cwsA);
            if (hasB)
                xconv(ps, ts, qvB, qoffB, wrB, cwsA);  // same cws as jobA
            // within-wave DS ordering: writes before reads; fence compiler
            asm volatile("s_waitcnt lgkmcnt(0)" ::: "memory");

            // ---- C: y-conv, stream 8 rows for both y-outputs ----
            const float4* rbase = &xw[wid][2 * tyo2][pcr];
#pragma unroll
            for (int r8 = 0; r8 < 8; ++r8) {
                float4 v = rbase[r8 * CP];
                v2f v01; v01[0] = v.x; v01[1] = v.y;
                v2f v23; v23[0] = v.z; v23[1] = v.w;
                if (r8 < 7) {
                    float w2 = gw.g[r8];
                    m01[0] = w2 * v01 + m01[0];
                    m23[0] = w2 * v23 + m23[0];
                }
                if (r8 > 0) {
                    float w2 = gw.g[r8 - 1];
                    m01[1] = w2 * v01 + m01[1];
                    m23[1] = w2 * v23 + m23[1];
                }
            }
        }

        // ---- z rings: consume slot0, shift+FMA, refill (always) ----
#pragma unroll
        for (int yo = 0; yo < 2; ++yo) {
            v2f v01 = m01[yo], v23 = m23[yo];
            v2f cons01 = gw.g[6] * v01 + r01[yo][0];
            v2f cons23 = gw.g[6] * v23 + r23[yo][0];
#pragma unroll
            for (int j = 0; j < 5; ++j) {
                r01[yo][j] = gw.g[5 - j] * v01 + r01[yo][j + 1];
                r23[yo][j] = gw.g[5 - j] * v23 + r23[yo][j + 1];
            }
            r01[yo][5] = gw.g[0] * v01;
            r23[yo][5] = gw.g[0] * v23;

            if (s >= zs + 3) {   // output z = s-3
                float mu1 = cons01[0], mu2 = cons01[1];
                float Eu  = cons23[0], Ew  = cons23[1];
                float mu12 = mu1 * mu2, mu1sq = mu1 * mu1, mu2sq = mu2 * mu2;
                float sumsq = 0.5f  * (Eu + Ew) - mu1sq - mu2sq; // s1+s2
                float s12   = 0.25f * (Eu - Ew) - mu12;          // sigma12
                float num = (2.f * mu12 + C1v) * (2.f * s12 + C2v);
                float den = (mu1sq + mu2sq + C1v) * (sumsq + C2v);
                ssum += num * __builtin_amdgcn_rcpf(den);
            }
        }
    }

    // ---- block reduction (4 waves; sole barrier, outside the loop) ----
#pragma unroll
    for (int off = 32; off > 0; off >>= 1)
        ssum += __shfl_down(ssum, off, 64);
    __shared__ float wsum[4];
    if ((tid & 63) == 0) wsum[tid >> 6] = ssum;
    __syncthreads();
    if (tid == 0)
        partial[flat] = wsum[0] + wsum[1] + wsum[2] + wsum[3];
}

__global__ __launch_bounds__(256) void ssim_final(
        const float* __restrict__ partial, float* __restrict__ out) {
    float s = 0.f;
    for (int i = threadIdx.x; i < NPART; i += 256) s += partial[i];
#pragma unroll
    for (int off = 32; off > 0; off >>= 1)
        s += __shfl_down(s, off, 64);
    __shared__ float wsum[4];
    int lane = threadIdx.x & 63, wid = threadIdx.x >> 6;
    if (lane == 0) wsum[wid] = s;
    __syncthreads();
    if (threadIdx.x == 0) {
        float tot = wsum[0] + wsum[1] + wsum[2] + wsum[3];
        out[0] = 1.0f - tot / (float)NEL;
    }
}

extern "C" void kernel_launch(void* const* d_in, const int* in_sizes, int n_in,
                              void* d_out, int out_size, void* d_ws, size_t ws_size,
                              hipStream_t stream) {
    const float* p = (const float*)d_in[0];
    const float* t = (const float*)d_in[1];
    float* out = (float*)d_out;
    float* partial = (float*)d_ws;   // NPART floats

    G7 gw;
    {
        double s = 0.0, sig = 7.0 / 6.0;
        double g[7];
        for (int i = 0; i < 7; ++i) {
            double d = (double)i - 3.0;
            g[i] = exp(-d * d / (2.0 * sig * sig));
            s += g[i];
        }
        for (int i = 0; i < 7; ++i) gw.g[i] = (float)(g[i] / s);
    }

    ssim_fused<<<NBLK, NTHR, 0, stream>>>(p, t, partial, gw);
    ssim_final<<<1, 256, 0, stream>>>(partial, out);
}